// Round 3
// baseline (1349.263 us; speedup 1.0000x reference)
//
#include <hip/hip_runtime.h>
#include <hip/hip_bf16.h>

#define D 64
#define TSTEPS 4

__device__ __forceinline__ float selu_f(float x) {
  const float sc = 1.0507009873554805f;
  const float scal = 1.7580993408473766f;  // sc * alpha
  return x > 0.f ? sc * x : scal * (__expf(x) - 1.f);
}
__device__ __forceinline__ float sigm_f(float x) {
  return 1.f / (1.f + __expf(-x));
}
__device__ __forceinline__ float tanh_f(float x) {
  return 1.f - 2.f / (__expf(2.f * x) + 1.f);
}
__device__ __forceinline__ unsigned short f2bf(float x) {
  union { float f; unsigned u; } v; v.f = x;
  unsigned r = v.u + 0x7fff + ((v.u >> 16) & 1);  // RNE
  return (unsigned short)(r >> 16);
}
__device__ __forceinline__ float bf2f(unsigned short x) {
  union { unsigned u; float f; } v; v.u = ((unsigned)x) << 16;
  return v.f;
}

// ---- setup: zero counts and g ----
__global__ void k_setup(int* __restrict__ counts, float* __restrict__ g, int E) {
  for (int i = blockIdx.x * blockDim.x + threadIdx.x; i < E; i += gridDim.x * blockDim.x)
    counts[i] = 0;
  int t = blockIdx.x * blockDim.x + threadIdx.x;
  if (t < D) g[t] = 0.f;
}

__global__ void k_hist(const int* __restrict__ sec, int* counts, int P) {
  int i = blockIdx.x * blockDim.x + threadIdx.x;
  if (i < P) atomicAdd(&counts[sec[i]], 1);
}

// single-block exclusive scan; cursor may alias counts (each slot read-then-written
// by the same thread).
__global__ void k_scan(const int* __restrict__ counts, int* __restrict__ offsets,
                       int* __restrict__ cursor, int E, int P) {
  __shared__ int lds[1024];
  int t = threadIdx.x;
  int per = (E + 1023) >> 10;
  int lo = t * per, hi = min(lo + per, E);
  int s = 0;
  for (int i = lo; i < hi; ++i) s += counts[i];
  lds[t] = s;
  __syncthreads();
  for (int d = 1; d < 1024; d <<= 1) {
    int v = (t >= d) ? lds[t - d] : 0;
    __syncthreads();
    lds[t] += v;
    __syncthreads();
  }
  int run = (t == 0) ? 0 : lds[t - 1];
  for (int i = lo; i < hi; ++i) {
    int c = counts[i];
    offsets[i] = run;
    cursor[i] = run;
    run += c;
  }
  if (t == 1023) offsets[E] = P;
}

__global__ void k_scatter(const int* __restrict__ fst, const int* __restrict__ sec,
                          int* cursor, int* __restrict__ sorted_first, int P) {
  int i = blockIdx.x * blockDim.x + threadIdx.x;
  if (i < P) {
    int e = sec[i];
    int pos = atomicAdd(&cursor[e], 1);
    sorted_first[pos] = fst[i];
  }
}

// build Wuv [64][128] = [W_top | W_bot], Wg [128][256], bg [256]
__global__ void k_prep(const float* __restrict__ Wmsg,
                       const float* __restrict__ gk, const float* __restrict__ grk,
                       const float* __restrict__ gb,
                       float* __restrict__ Wuv, float* __restrict__ Wg, float* __restrict__ bg) {
  int i = blockIdx.x * blockDim.x + threadIdx.x;
  if (i < 64 * 128) {
    int k = i >> 7, c = i & 127;
    Wuv[i] = (c < 64) ? Wmsg[k * 64 + c] : Wmsg[(64 + k) * 64 + (c - 64)];
  }
  if (i < 128 * 256) {
    int r = i >> 8, c = i & 255;
    float v;
    if (r < 64) {
      v = (c < 192) ? gk[r * 192 + c] : 0.f;
    } else {
      int rr = r - 64;
      if (c < 128) v = grk[rr * 192 + c];
      else if (c < 192) v = 0.f;
      else v = grk[rr * 192 + (c - 64)];
    }
    Wg[i] = v;
  }
  if (i < 256) {
    float v;
    if (i < 128) v = gb[i] + gb[192 + i];
    else if (i < 192) v = gb[i];
    else v = gb[i + 128];
    bg[i] = v;
  }
}

// UV = h @ [W_top|W_bot]  (V part gets +b_msg) -- used once on initial link_state
template <int UV16>
__global__ __launch_bounds__(256) void k_uv(const float* __restrict__ h,
                                            const float* __restrict__ Wuv,
                                            const float* __restrict__ bmsg,
                                            void* __restrict__ UVp, int E) {
  __shared__ float As[32 * 65];
  int t = threadIdx.x;
  int base = blockIdx.x * 32;
  for (int q = t; q < 32 * 16; q += 256) {
    int row = q >> 4, k4 = (q & 15) << 2;
    float4 v = make_float4(0.f, 0.f, 0.f, 0.f);
    if (base + row < E)
      v = *reinterpret_cast<const float4*>(h + (size_t)(base + row) * 64 + k4);
    As[row * 65 + k4 + 0] = v.x;
    As[row * 65 + k4 + 1] = v.y;
    As[row * 65 + k4 + 2] = v.z;
    As[row * 65 + k4 + 3] = v.w;
  }
  __syncthreads();
  int ct = t & 31, eg = t >> 5;
  int c0 = ct * 4;
  float4 binit = make_float4(0.f, 0.f, 0.f, 0.f);
  if (c0 >= 64) binit = *reinterpret_cast<const float4*>(bmsg + (c0 - 64));
  float4 acc[4];
  acc[0] = binit; acc[1] = binit; acc[2] = binit; acc[3] = binit;
#pragma unroll 8
  for (int k = 0; k < 64; ++k) {
    float4 bv = *reinterpret_cast<const float4*>(Wuv + k * 128 + c0);
#pragma unroll
    for (int j = 0; j < 4; ++j) {
      float a = As[(eg + j * 8) * 65 + k];
      acc[j].x += a * bv.x; acc[j].y += a * bv.y;
      acc[j].z += a * bv.z; acc[j].w += a * bv.w;
    }
  }
#pragma unroll
  for (int j = 0; j < 4; ++j) {
    int e = base + eg + j * 8;
    if (e < E) {
      if constexpr (UV16) {
        ushort4 s;
        s.x = f2bf(acc[j].x); s.y = f2bf(acc[j].y);
        s.z = f2bf(acc[j].z); s.w = f2bf(acc[j].w);
        *reinterpret_cast<ushort4*>((unsigned short*)UVp + (size_t)e * 128 + c0) = s;
      } else {
        *reinterpret_cast<float4*>((float*)UVp + (size_t)e * 128 + c0) = acc[j];
      }
    }
  }
}

// per-edge aggregation: agg[e] = sum over sorted pairs of selu(U[f] + V[e])
template <int UV16, int AGG16>
__global__ __launch_bounds__(256) void k_pair(const void* __restrict__ UVp,
                                              const int* __restrict__ offsets,
                                              const int* __restrict__ sorted_first,
                                              void* __restrict__ aggp, int E) {
  int w = (blockIdx.x << 2) + (threadIdx.x >> 6);
  if (w >= E) return;
  int c = threadIdx.x & 63;
  const float* UV32 = (const float*)UVp;
  const unsigned short* UV16p = (const unsigned short*)UVp;
  float base;
  if constexpr (UV16) base = bf2f(UV16p[(size_t)w * 128 + 64 + c]);
  else                base = UV32[(size_t)w * 128 + 64 + c];
  int i = offsets[w], end = offsets[w + 1];
  float acc = 0.f;
  for (; i + 3 < end; i += 4) {
    int f0 = sorted_first[i];
    int f1 = sorted_first[i + 1];
    int f2 = sorted_first[i + 2];
    int f3 = sorted_first[i + 3];
    float u0, u1, u2, u3;
    if constexpr (UV16) {
      u0 = bf2f(UV16p[(size_t)f0 * 128 + c]);
      u1 = bf2f(UV16p[(size_t)f1 * 128 + c]);
      u2 = bf2f(UV16p[(size_t)f2 * 128 + c]);
      u3 = bf2f(UV16p[(size_t)f3 * 128 + c]);
    } else {
      u0 = UV32[(size_t)f0 * 128 + c];
      u1 = UV32[(size_t)f1 * 128 + c];
      u2 = UV32[(size_t)f2 * 128 + c];
      u3 = UV32[(size_t)f3 * 128 + c];
    }
    acc += selu_f(u0 + base);
    acc += selu_f(u1 + base);
    acc += selu_f(u2 + base);
    acc += selu_f(u3 + base);
  }
  for (; i < end; ++i) {
    int f0 = sorted_first[i];
    float u;
    if constexpr (UV16) u = bf2f(UV16p[(size_t)f0 * 128 + c]);
    else                u = UV32[(size_t)f0 * 128 + c];
    acc += selu_f(u + base);
  }
  if constexpr (AGG16)
    ((unsigned short*)aggp)[(size_t)w * 64 + c] = f2bf(acc);
  else
    ((float*)aggp)[(size_t)w * 64 + c] = acc;
}

// Fused GRU + next-iteration UV + (optionally) readout column-sum.
template <int UV16, int AGG16>
__global__ __launch_bounds__(256) void k_gru(const void* __restrict__ aggp,
                                             const float* __restrict__ h_in,
                                             float* __restrict__ h_out,
                                             const float* __restrict__ Wg,
                                             const float* __restrict__ bg,
                                             const float* __restrict__ Wuv,
                                             const float* __restrict__ bmsg,
                                             void* __restrict__ UVp,
                                             float* __restrict__ g,
                                             int E, int write_uv, int accum_g) {
  __shared__ float As[32 * 129];   // [agg | h] staging; h slot later holds h_new
  __shared__ float Ms[32 * 257];   // GEMM output M
  __shared__ float red[256];
  int t = threadIdx.x;
  int base = blockIdx.x * 32;

  // ---- phase 1: stage [agg | h_in] ----
  for (int q = t; q < 32 * 32; q += 256) {
    int row = q >> 5, c4 = (q & 31) << 2;
    int e = base + row;
    float4 v = make_float4(0.f, 0.f, 0.f, 0.f);
    if (e < E) {
      if (c4 < 64) {
        if constexpr (AGG16) {
          ushort4 s = *reinterpret_cast<const ushort4*>(
              (const unsigned short*)aggp + (size_t)e * 64 + c4);
          v = make_float4(bf2f(s.x), bf2f(s.y), bf2f(s.z), bf2f(s.w));
        } else {
          v = *reinterpret_cast<const float4*>((const float*)aggp + (size_t)e * 64 + c4);
        }
      } else {
        v = *reinterpret_cast<const float4*>(h_in + (size_t)e * 64 + (c4 - 64));
      }
    }
    As[row * 129 + c4 + 0] = v.x;
    As[row * 129 + c4 + 1] = v.y;
    As[row * 129 + c4 + 2] = v.z;
    As[row * 129 + c4 + 3] = v.w;
  }
  __syncthreads();

  // ---- phase 2: M = As @ Wg, wave wv owns cols [wv*64, wv*64+64) ----
  // cols 0..127 (z,r): k 0..127; cols 128..191 (mx2): k 0..63; cols 192..255 (mi2): k 64..127
  {
    int wv = t >> 6;
    int lane = t & 63;
    int ct8 = lane & 7;
    int rg = lane >> 3;
    int c0 = wv * 64 + ct8 * 8;
    int kbeg = (wv == 3) ? 64 : 0;
    int kend = (wv == 2) ? 64 : 128;
    float4 b0 = *reinterpret_cast<const float4*>(bg + c0);
    float4 b1 = *reinterpret_cast<const float4*>(bg + c0 + 4);
    float4 acc0[4], acc1[4];
#pragma unroll
    for (int j = 0; j < 4; ++j) { acc0[j] = b0; acc1[j] = b1; }
#pragma unroll 4
    for (int k = kbeg; k < kend; ++k) {
      float4 bv0 = *reinterpret_cast<const float4*>(Wg + k * 256 + c0);
      float4 bv1 = *reinterpret_cast<const float4*>(Wg + k * 256 + c0 + 4);
#pragma unroll
      for (int j = 0; j < 4; ++j) {
        float a = As[(rg + j * 8) * 129 + k];
        acc0[j].x += a * bv0.x; acc0[j].y += a * bv0.y;
        acc0[j].z += a * bv0.z; acc0[j].w += a * bv0.w;
        acc1[j].x += a * bv1.x; acc1[j].y += a * bv1.y;
        acc1[j].z += a * bv1.z; acc1[j].w += a * bv1.w;
      }
    }
#pragma unroll
    for (int j = 0; j < 4; ++j) {
      float* m = Ms + (rg + j * 8) * 257 + c0;
      m[0] = acc0[j].x; m[1] = acc0[j].y; m[2] = acc0[j].z; m[3] = acc0[j].w;
      m[4] = acc1[j].x; m[5] = acc1[j].y; m[6] = acc1[j].z; m[7] = acc1[j].w;
    }
  }
  __syncthreads();

  // ---- phase 3: gate epilogue; h_new -> global + As h-slot; g partials ----
  float gsum = 0.f;
#pragma unroll
  for (int j = 0; j < 8; ++j) {
    int u = t + 256 * j;
    int e = u >> 6, c = u & 63;
    int ge = base + e;
    float mz = Ms[e * 257 + c];
    float mr = Ms[e * 257 + 64 + c];
    float mx2 = Ms[e * 257 + 128 + c];
    float mi2 = Ms[e * 257 + 192 + c];
    float hold = As[e * 129 + 64 + c];
    float z = sigm_f(mz);
    float r = sigm_f(mr);
    float hh = tanh_f(mx2 + r * mi2);
    float hn = z * hold + (1.f - z) * hh;
    if (ge < E) {
      h_out[(size_t)ge * 64 + c] = hn;
    } else {
      hn = 0.f;
    }
    As[e * 129 + 64 + c] = hn;
    gsum += hn;
  }
  __syncthreads();

  // ---- phase 4: UV = [h_new @ W_top | h_new @ W_bot + bmsg] ----
  if (write_uv) {
    int ct = t & 31, eg = t >> 5;
    int c0 = ct * 4;
    float4 binit = make_float4(0.f, 0.f, 0.f, 0.f);
    if (c0 >= 64) binit = *reinterpret_cast<const float4*>(bmsg + (c0 - 64));
    float4 acc[4];
    acc[0] = binit; acc[1] = binit; acc[2] = binit; acc[3] = binit;
#pragma unroll 8
    for (int k = 0; k < 64; ++k) {
      float4 bv = *reinterpret_cast<const float4*>(Wuv + k * 128 + c0);
#pragma unroll
      for (int j = 0; j < 4; ++j) {
        float a = As[(eg + j * 8) * 129 + 64 + k];
        acc[j].x += a * bv.x; acc[j].y += a * bv.y;
        acc[j].z += a * bv.z; acc[j].w += a * bv.w;
      }
    }
#pragma unroll
    for (int j = 0; j < 4; ++j) {
      int e = base + eg + j * 8;
      if (e < E) {
        if constexpr (UV16) {
          ushort4 s;
          s.x = f2bf(acc[j].x); s.y = f2bf(acc[j].y);
          s.z = f2bf(acc[j].z); s.w = f2bf(acc[j].w);
          *reinterpret_cast<ushort4*>((unsigned short*)UVp + (size_t)e * 128 + c0) = s;
        } else {
          *reinterpret_cast<float4*>((float*)UVp + (size_t)e * 128 + c0) = acc[j];
        }
      }
    }
  }

  // ---- phase 5: readout column-sum accumulation (last iteration only) ----
  if (accum_g) {
    red[t] = gsum;
    __syncthreads();
    if (t < 64) atomicAdd(&g[t], red[t] + red[t + 64] + red[t + 128] + red[t + 192]);
  }
}

__global__ __launch_bounds__(256) void k_mlp(const float* __restrict__ g,
                                             const float* __restrict__ W1, const float* __restrict__ b1,
                                             const float* __restrict__ W2, const float* __restrict__ b2,
                                             const float* __restrict__ W3, const float* __restrict__ b3,
                                             float* __restrict__ out) {
  __shared__ float gs[64];
  __shared__ float h1[256];
  __shared__ float h2[256];
  __shared__ float red[256];
  int t = threadIdx.x;
  if (t < 64) gs[t] = g[t];
  __syncthreads();
  float acc = b1[t];
#pragma unroll
  for (int k = 0; k < 64; ++k) acc += gs[k] * W1[k * 256 + t];
  h1[t] = selu_f(acc);
  __syncthreads();
  acc = b2[t];
#pragma unroll 8
  for (int k = 0; k < 256; ++k) acc += h1[k] * W2[k * 256 + t];
  h2[t] = selu_f(acc);
  __syncthreads();
  red[t] = h2[t] * W3[t];
  __syncthreads();
  for (int d = 128; d > 0; d >>= 1) {
    if (t < d) red[t] += red[t + d];
    __syncthreads();
  }
  if (t == 0) out[0] = red[0] + b3[0];
}

extern "C" void kernel_launch(void* const* d_in, const int* in_sizes, int n_in,
                              void* d_out, int out_size, void* d_ws, size_t ws_size,
                              hipStream_t stream) {
  const float* ls   = (const float*)d_in[0];
  const int*   fst  = (const int*)d_in[1];
  const int*   sec  = (const int*)d_in[2];
  const float* Wmsg = (const float*)d_in[4];
  const float* bmsg = (const float*)d_in[5];
  const float* gk   = (const float*)d_in[6];
  const float* grk  = (const float*)d_in[7];
  const float* gb   = (const float*)d_in[8];
  const float* W1   = (const float*)d_in[9];
  const float* b1   = (const float*)d_in[10];
  const float* W2   = (const float*)d_in[11];
  const float* b2   = (const float*)d_in[12];
  const float* W3   = (const float*)d_in[13];
  const float* b3   = (const float*)d_in[14];
  int E = in_sizes[0] / D;
  int P = in_sizes[1];
  float* out = (float*)d_out;
  (void)n_in; (void)out_size;

  // ---- ws_size-aware tiered layout (decision depends only on ws_size: graph-safe)
  // Tier 0: fp32 UV, fp32 agg (~110 MB). Tier 1: bf16 UV (~84 MB).
  // Tier 2: bf16 UV + bf16 agg (~71 MB). Round-2 failure diagnosed as ws overflow
  // corrupting the harness's pristine input copies -> never exceed ws_size.
  auto total_need = [&](int uv16, int agg16) -> size_t {
    size_t o = 0;
    auto add = [&](size_t b) { o = (o + b + 255) & ~(size_t)255; };
    add((size_t)E * 64 * 4);                    // h
    add((size_t)E * 128 * (uv16 ? 2 : 4));      // UV
    add((size_t)E * 64 * (agg16 ? 2 : 4));      // agg
    add(((size_t)E + 1) * 4);                   // offsets
    add((size_t)E * 4);                         // counts (aliased by cursor)
    add((size_t)P * 4);                         // sorted_first
    add(64 * 128 * 4);                          // Wuv
    add(128 * 256 * 4);                         // Wg
    add(256 * 4);                               // bg
    add(64 * 4);                                // g
    return o;
  };
  int uv16 = 0, agg16 = 0;
  if (total_need(0, 0) > ws_size) { uv16 = 1; }
  if (uv16 && total_need(1, 0) > ws_size) { agg16 = 1; }
  // If even tier 2 doesn't fit, run it anyway (best effort).

  char* ws = (char*)d_ws;
  size_t off = 0;
  auto alloc = [&](size_t bytes) {
    void* p = ws + off;
    off = (off + bytes + 255) & ~(size_t)255;
    return p;
  };
  float* h            = (float*)alloc((size_t)E * 64 * 4);
  void*  UV           = alloc((size_t)E * 128 * (uv16 ? 2 : 4));
  void*  agg          = alloc((size_t)E * 64 * (agg16 ? 2 : 4));
  int*   offsets      = (int*)alloc(((size_t)E + 1) * 4);
  int*   counts       = (int*)alloc((size_t)E * 4);
  int*   cursor       = counts;  // alias: k_scan reads-then-writes each slot in-thread
  int*   sorted_first = (int*)alloc((size_t)P * 4);
  float* Wuv          = (float*)alloc(64 * 128 * 4);
  float* Wg           = (float*)alloc(128 * 256 * 4);
  float* bg           = (float*)alloc(256 * 4);
  float* g            = (float*)alloc(64 * 4);

  k_setup<<<512, 256, 0, stream>>>(counts, g, E);
  k_hist<<<(P + 255) / 256, 256, 0, stream>>>(sec, counts, P);
  k_scan<<<1, 1024, 0, stream>>>(counts, offsets, cursor, E, P);
  k_scatter<<<(P + 255) / 256, 256, 0, stream>>>(fst, sec, cursor, sorted_first, P);
  k_prep<<<128, 256, 0, stream>>>(Wmsg, gk, grk, gb, Wuv, Wg, bg);

  int gemm_blocks = (E + 31) / 32;
  int pair_blocks = (E + 3) / 4;

  if (!uv16) {
    k_uv<0><<<gemm_blocks, 256, 0, stream>>>(ls, Wuv, bmsg, UV, E);
    for (int it = 0; it < TSTEPS; ++it) {
      const float* hin = (it == 0) ? ls : h;
      int last = (it == TSTEPS - 1);
      k_pair<0, 0><<<pair_blocks, 256, 0, stream>>>(UV, offsets, sorted_first, agg, E);
      k_gru<0, 0><<<gemm_blocks, 256, 0, stream>>>(agg, hin, h, Wg, bg, Wuv, bmsg, UV, g,
                                                   E, !last, last);
    }
  } else if (!agg16) {
    k_uv<1><<<gemm_blocks, 256, 0, stream>>>(ls, Wuv, bmsg, UV, E);
    for (int it = 0; it < TSTEPS; ++it) {
      const float* hin = (it == 0) ? ls : h;
      int last = (it == TSTEPS - 1);
      k_pair<1, 0><<<pair_blocks, 256, 0, stream>>>(UV, offsets, sorted_first, agg, E);
      k_gru<1, 0><<<gemm_blocks, 256, 0, stream>>>(agg, hin, h, Wg, bg, Wuv, bmsg, UV, g,
                                                   E, !last, last);
    }
  } else {
    k_uv<1><<<gemm_blocks, 256, 0, stream>>>(ls, Wuv, bmsg, UV, E);
    for (int it = 0; it < TSTEPS; ++it) {
      const float* hin = (it == 0) ? ls : h;
      int last = (it == TSTEPS - 1);
      k_pair<1, 1><<<pair_blocks, 256, 0, stream>>>(UV, offsets, sorted_first, agg, E);
      k_gru<1, 1><<<gemm_blocks, 256, 0, stream>>>(agg, hin, h, Wg, bg, Wuv, bmsg, UV, g,
                                                   E, !last, last);
    }
  }
  k_mlp<<<1, 256, 0, stream>>>(g, W1, b1, W2, b2, W3, b3, out);
}